// Round 9
// baseline (988.117 us; speedup 1.0000x reference)
//
#include <hip/hip_runtime.h>
#include <hip/hip_bf16.h>

typedef unsigned short u16;
typedef __attribute__((ext_vector_type(8))) short short8;
typedef __attribute__((ext_vector_type(4))) float floatx4;

__device__ __forceinline__ float bf2f(u16 u) {
    unsigned x = (unsigned)u << 16;
    return __uint_as_float(x);
}
__device__ __forceinline__ u16 f2bf(float f) {   // round-to-nearest-even
    unsigned x = __float_as_uint(f);
    unsigned r = (x + 0x7fffu + ((x >> 16) & 1u)) >> 16;
    return (u16)r;
}

__device__ __forceinline__ float wave_sum(float v) {
    #pragma unroll
    for (int off = 32; off; off >>= 1) v += __shfl_xor(v, off);
    return v;
}

// async global->LDS, 16B per lane; lds base must be wave-uniform (HW adds lane*16)
__device__ __forceinline__ void async16(const u16* g, const u16* lds) {
    __builtin_amdgcn_global_load_lds(
        (const __attribute__((address_space(1))) void*)g,
        (__attribute__((address_space(3))) void*)lds, 16, 0, 0);
}

// fp32 -> (hi, lo) bf16 split (8 elems). lo = bf16(v - fp32(hi)) exactly.
__device__ __forceinline__ void hilo8(const float* p, u16* hi, u16* lo) {
    float4 a = *(const float4*)p, b = *(const float4*)(p + 4);
    float v[8] = {a.x, a.y, a.z, a.w, b.x, b.y, b.z, b.w};
    #pragma unroll
    for (int i = 0; i < 8; ++i) {
        u16 h = f2bf(v[i]);
        hi[i] = h;
        lo[i] = f2bf(v[i] - bf2f(h));
    }
}

// whole-tensor fp32 -> hi/lo bf16 planes (8 elems/thread, coalesced)
__global__ __launch_bounds__(256) void hilo_conv_kernel(
    const float* __restrict__ in, u16* __restrict__ hi, u16* __restrict__ lo)
{
    const size_t i = ((size_t)blockIdx.x * 256 + threadIdx.x) * 8;
    u16 h[8], l[8];
    hilo8(in + i, h, l);
    *(uint4*)&hi[i] = *(const uint4*)h;
    *(uint4*)&lo[i] = *(const uint4*)l;
}

// ---------------------------------------------------------------------------
// bf16 MFMA GEMM body: C = act(A @ B + bias). Bt = B^T [N][K] bf16.
// 128x128 tile / 256 threads / 4 waves. BK=32 DOUBLE-buffered (32 KB LDS,
// same footprint as the single-buffered BK=64 form -> occupancy preserved),
// T4 counted-vmcnt pipeline: raw s_barrier + explicit s_waitcnt vmcnt(4)
// instead of __syncthreads()'s vmcnt(0) drain. Next tile's 4 global_load_lds
// stay in flight across the compute phase (R8 showed the drain, not HBM BW,
// was the cost: h1 at 0.95 TB/s / MfmaUtil 12%).
// Race-freedom: buf b written at iter j+1 was last read at iter j-1, with two
// barriers between; per-wave vmcnt(4) before barrier 1 => buf j complete
// block-wide. Trailing barrier needs no drain (ds_reads consumed by MFMAs).
// K must be a multiple of 32. transC: Cb written V-transposed.
// ---------------------------------------------------------------------------
__device__ __forceinline__ void gemm_body(
    const u16* __restrict__ A, int lda,
    const u16* __restrict__ Bt, int ldb,
    const float* __restrict__ bias,
    float* __restrict__ Cf, u16* __restrict__ Cb, int ldc,
    int K, int act, int transC, int m0, int n0)
{
    __shared__ __align__(16) u16 Asm[2][4096];   // [buf][128 x 32]
    __shared__ __align__(16) u16 Bsm[2][4096];

    const int tid = threadIdx.x;
    const int lane = tid & 63;
    const int wave = tid >> 6;
    const int wm = (wave >> 1) * 64, wn = (wave & 1) * 64;

    const int r0 = tid >> 2;
    const int kc = (tid & 3) * 8;
    const int kq = (lane >> 4) * 8;
    const int fm = lane & 15;

    const floatx4 zz = {0.f, 0.f, 0.f, 0.f};
    floatx4 acc[4][4];
    #pragma unroll
    for (int mt = 0; mt < 4; ++mt)
        #pragma unroll
        for (int nt = 0; nt < 4; ++nt) acc[mt][nt] = zz;

    auto stage = [&](int kt, int b) {
        async16(&A[(size_t)(m0 + r0) * lda + kt + kc],      &Asm[b][wave * 512]);
        async16(&A[(size_t)(m0 + r0 + 64) * lda + kt + kc], &Asm[b][2048 + wave * 512]);
        async16(&Bt[(size_t)(n0 + r0) * ldb + kt + kc],      &Bsm[b][wave * 512]);
        async16(&Bt[(size_t)(n0 + r0 + 64) * ldb + kt + kc], &Bsm[b][2048 + wave * 512]);
    };

    stage(0, 0);

    for (int kt = 0; kt < K; kt += 32) {
        const int cur = (kt >> 5) & 1;
        const bool more = (kt + 32 < K);
        if (more) {
            stage(kt + 32, cur ^ 1);                       // 4 loads in flight
            asm volatile("s_waitcnt vmcnt(4)" ::: "memory");  // my buf[cur] loads done
        } else {
            asm volatile("s_waitcnt vmcnt(0)" ::: "memory");
        }
        __builtin_amdgcn_s_barrier();                      // buf[cur] complete block-wide
        __builtin_amdgcn_sched_barrier(0);

        short8 af[4], bfr[4];
        #pragma unroll
        for (int mt = 0; mt < 4; ++mt)
            af[mt] = *(const short8*)&Asm[cur][(wm + mt * 16 + fm) * 32 + kq];
        #pragma unroll
        for (int nt = 0; nt < 4; ++nt)
            bfr[nt] = *(const short8*)&Bsm[cur][(wn + nt * 16 + fm) * 32 + kq];

        #pragma unroll
        for (int mt = 0; mt < 4; ++mt)
            #pragma unroll
            for (int nt = 0; nt < 4; ++nt)
                acc[mt][nt] = __builtin_amdgcn_mfma_f32_16x16x32_bf16(
                    af[mt], bfr[nt], acc[mt][nt], 0, 0, 0);

        if (more) {                                        // publish: iter j+1 overwrites cur
            __builtin_amdgcn_s_barrier();                  // raw: next-tile loads stay in flight
            __builtin_amdgcn_sched_barrier(0);
        }
    }

    const int cr = (lane >> 4) * 4;
    #pragma unroll
    for (int mt = 0; mt < 4; ++mt) {
        #pragma unroll
        for (int nt = 0; nt < 4; ++nt) {
            const int col = n0 + wn + nt * 16 + fm;
            const float bz = bias ? bias[col] : 0.f;
            #pragma unroll
            for (int r = 0; r < 4; ++r) {
                const int row = m0 + wm + mt * 16 + cr + r;
                float v = acc[mt][nt][r] + bz;
                if (act) v = fmaxf(v, 0.f);
                if (Cf) Cf[(size_t)row * ldc + col] = v;
                if (Cb) {
                    if (transC)
                        Cb[(((size_t)(row >> 10) * 512 + col) << 10) + (row & 1023)] = f2bf(v);
                    else
                        Cb[(size_t)row * ldc + col] = f2bf(v);
                }
            }
        }
    }
}

// XCD-swizzled launcher. 1-D grid of NT*32*NZ blocks; panels (m,z) = 32*NZ
// divisible by 8. The NT n-tiles sharing one A-panel land on one XCD
// (hw: xcd = wgid % 8) -> A re-reads hit that XCD's L2.
template <typename TA>
__global__ __launch_bounds__(256) void gemm_bf16(
    const TA* __restrict__ A, int lda, long strideAz,
    const u16* __restrict__ Bt, int ldb, long strideBz,
    const float* __restrict__ bias, int strideBiasZ,
    float* __restrict__ Cf, u16* __restrict__ Cb, int ldc, long strideCz,
    int K, int act, int transC, int NT)
{
    const int wg   = blockIdx.x;
    const int xcd  = wg & 7;
    const int slot = wg >> 3;
    const int nt   = slot % NT;
    const int pg   = slot / NT;
    const int panel = xcd + 8 * pg;      // 0 .. 32*NZ-1
    const int my = panel & 31, mz = panel >> 5;

    A  += (size_t)mz * strideAz;
    Bt += (size_t)mz * strideBz;
    const float* bz = bias ? bias + (size_t)mz * strideBiasZ : nullptr;
    if (Cf) Cf += (size_t)mz * strideCz;
    if (Cb) Cb += (size_t)mz * strideCz;
    gemm_body(A, lda, Bt, ldb, bz, Cf, Cb, ldc, K, act, transC, my * 128, nt * 128);
}

// Fused K+V projection, swizzled. 256 blocks: panel mz=0 -> khb = xb @ kw,
// mz=1 -> vhT = trans(yb @ vw).
__global__ __launch_bounds__(256) void gemm_kv(
    const u16* __restrict__ xb, const u16* __restrict__ yb,
    const u16* __restrict__ kwt, const u16* __restrict__ vwt,
    const float* __restrict__ kb, const float* __restrict__ vb,
    u16* __restrict__ khb, u16* __restrict__ vhT)
{
    const int wg   = blockIdx.x;
    const int xcd  = wg & 7;
    const int slot = wg >> 3;
    const int nt   = slot & 3;           // NT = 4
    const int pg   = slot >> 2;
    const int panel = xcd + 8 * pg;      // 0..63
    const int my = panel & 31, mz = panel >> 5;

    if (mz == 0)
        gemm_body(xb, 512, kwt, 512, kb, nullptr, khb, 512, 512, 0, 0, my * 128, nt * 128);
    else
        gemm_body(yb, 512, vwt, 512, vb, nullptr, vhT, 512, 512, 0, 1, my * 128, nt * 128);
}

// ---------------------------------------------------------------------------
// Split-precision MFMA GEMM for the gate/adapter path (top-k is discontinuous,
// so plain bf16 is not enough). 3-term: C = Ah@Bh + Al@Bh + Ah@Bl.
// 128x128 tile, BK=32 double-buffered (4 streams x 2 bufs = 64 KB, same as
// before), counted-vmcnt pipeline like gemm_body (vmcnt(8): 8 loads/stage).
// XCD-swizzled 1-D grid of 512.
// ---------------------------------------------------------------------------
__global__ __launch_bounds__(256) void gemm_f32split(
    const u16* __restrict__ Ah, const u16* __restrict__ Al, int lda,
    const u16* __restrict__ Bh, const u16* __restrict__ Bl, int ldb,
    float* __restrict__ Cf, int ldc, long strideCz,
    int kz)
{
    __shared__ __align__(16) u16 Ahs[2][4096];
    __shared__ __align__(16) u16 Als[2][4096];
    __shared__ __align__(16) u16 Bhs[2][4096];
    __shared__ __align__(16) u16 Bls[2][4096];

    const int wg   = blockIdx.x;
    const int xcd  = wg & 7;
    const int slot = wg >> 3;            // 0..63
    const int nt4  = slot & 3;           // n-tile within A-group
    const int g    = xcd + 8 * (slot >> 2);   // A-group 0..127
    const int my   = g & 31, mz = g >> 5;

    const int tid = threadIdx.x;
    const int lane = tid & 63;
    const int wave = tid >> 6;
    const int m0 = my * 128, n0 = nt4 * 128;
    const int wm = (wave >> 1) * 64, wn = (wave & 1) * 64;
    const int k0 = mz * kz;
    Cf += (size_t)mz * strideCz;

    const int r0 = tid >> 2;
    const int kc = (tid & 3) * 8;
    const int kq = (lane >> 4) * 8;
    const int fm = lane & 15;

    const floatx4 zz = {0.f, 0.f, 0.f, 0.f};
    floatx4 acc[4][4];
    #pragma unroll
    for (int mt = 0; mt < 4; ++mt)
        #pragma unroll
        for (int nt = 0; nt < 4; ++nt) acc[mt][nt] = zz;

    auto stage = [&](int kt, int b) {
        const size_t ka = (size_t)(m0 + r0) * lda + k0 + kt + kc;
        const size_t kb = (size_t)(n0 + r0) * ldb + k0 + kt + kc;
        async16(&Ah[ka],                    &Ahs[b][wave * 512]);
        async16(&Ah[ka + (size_t)64 * lda], &Ahs[b][2048 + wave * 512]);
        async16(&Al[ka],                    &Als[b][wave * 512]);
        async16(&Al[ka + (size_t)64 * lda], &Als[b][2048 + wave * 512]);
        async16(&Bh[kb],                    &Bhs[b][wave * 512]);
        async16(&Bh[kb + (size_t)64 * ldb], &Bhs[b][2048 + wave * 512]);
        async16(&Bl[kb],                    &Bls[b][wave * 512]);
        async16(&Bl[kb + (size_t)64 * ldb], &Bls[b][2048 + wave * 512]);
    };

    stage(0, 0);

    for (int kt = 0; kt < kz; kt += 32) {
        const int cur = (kt >> 5) & 1;
        const bool more = (kt + 32 < kz);
        if (more) {
            stage(kt + 32, cur ^ 1);
            asm volatile("s_waitcnt vmcnt(8)" ::: "memory");
        } else {
            asm volatile("s_waitcnt vmcnt(0)" ::: "memory");
        }
        __builtin_amdgcn_s_barrier();
        __builtin_amdgcn_sched_barrier(0);

        short8 ah[4], al[4], bh[4], bl[4];
        #pragma unroll
        for (int mt = 0; mt < 4; ++mt) {
            ah[mt] = *(const short8*)&Ahs[cur][(wm + mt * 16 + fm) * 32 + kq];
            al[mt] = *(const short8*)&Als[cur][(wm + mt * 16 + fm) * 32 + kq];
        }
        #pragma unroll
        for (int nt = 0; nt < 4; ++nt) {
            bh[nt] = *(const short8*)&Bhs[cur][(wn + nt * 16 + fm) * 32 + kq];
            bl[nt] = *(const short8*)&Bls[cur][(wn + nt * 16 + fm) * 32 + kq];
        }

        #pragma unroll
        for (int mt = 0; mt < 4; ++mt)
            #pragma unroll
            for (int nt = 0; nt < 4; ++nt) {
                acc[mt][nt] = __builtin_amdgcn_mfma_f32_16x16x32_bf16(
                    ah[mt], bh[nt], acc[mt][nt], 0, 0, 0);
                acc[mt][nt] = __builtin_amdgcn_mfma_f32_16x16x32_bf16(
                    al[mt], bh[nt], acc[mt][nt], 0, 0, 0);
                acc[mt][nt] = __builtin_amdgcn_mfma_f32_16x16x32_bf16(
                    ah[mt], bl[nt], acc[mt][nt], 0, 0, 0);
            }

        if (more) {
            __builtin_amdgcn_s_barrier();
            __builtin_amdgcn_sched_barrier(0);
        }
    }

    const int cr = (lane >> 4) * 4;
    #pragma unroll
    for (int mt = 0; mt < 4; ++mt) {
        #pragma unroll
        for (int nt = 0; nt < 4; ++nt) {
            const int col = n0 + wn + nt * 16 + fm;
            #pragma unroll
            for (int r = 0; r < 4; ++r) {
                const int row = m0 + wm + mt * 16 + cr + r;
                Cf[(size_t)row * ldc + col] = acc[mt][nt][r];
            }
        }
    }
}

// ---------------------------------------------------------------------------
// Fused: summary-row = relu(sum of 4 split-K partials + bias), then gate
// logits + top-2 softmax. One block per row.
// ---------------------------------------------------------------------------
__global__ __launch_bounds__(64) void gate_fused_kernel(
    const float* __restrict__ ps, const float* __restrict__ adapt_b,
    const float* __restrict__ m_seq,
    const float* __restrict__ gw, const float* __restrict__ gb,
    float* __restrict__ gates)
{
    const int r = blockIdx.x, t = threadIdx.x;
    float p0 = 0.f, p1 = 0.f, p2 = 0.f, p3 = 0.f;
    const float* pr = ps + (size_t)r * 512;
    for (int j = t; j < 512; j += 64) {
        float v = pr[j] + pr[j + 2097152] + pr[j + 4194304] + pr[j + 6291456] + adapt_b[j];
        float s = fmaxf(v, 0.f);
        const float* g = gw + (size_t)j * 4;
        p0 += s * g[0]; p1 += s * g[1]; p2 += s * g[2]; p3 += s * g[3];
    }
    {
        float m = m_seq[(size_t)r * 64 + t];
        const float* g = gw + (size_t)(512 + t) * 4;
        p0 += m * g[0]; p1 += m * g[1]; p2 += m * g[2]; p3 += m * g[3];
    }
    p0 = wave_sum(p0); p1 = wave_sum(p1); p2 = wave_sum(p2); p3 = wave_sum(p3);
    if (t == 0) {
        float lg[4] = { p0 + gb[0], p1 + gb[1], p2 + gb[2], p3 + gb[3] };
        float m1 = -INFINITY, m2 = -INFINITY;
        #pragma unroll
        for (int k = 0; k < 4; ++k) {
            float v = lg[k];
            if (v > m1) { m2 = m1; m1 = v; }
            else if (v > m2) { m2 = v; }
        }
        float wv[4], s = 0.f;
        #pragma unroll
        for (int k = 0; k < 4; ++k) {
            wv[k] = (lg[k] >= m2) ? __expf(lg[k] - m1) : 0.f;
            s += wv[k];
        }
        float inv = 1.f / s;
        #pragma unroll
        for (int k = 0; k < 4; ++k) gates[(size_t)r * 4 + k] = wv[k] * inv;
    }
}

// ---------------------------------------------------------------------------
__global__ __launch_bounds__(256) void tconv_kernel(
    const float* __restrict__ in, u16* __restrict__ out, int K, int N)
{
    __shared__ float t[32][33];
    const int n0 = blockIdx.x * 32, k0 = blockIdx.y * 32;
    const size_t bo = (size_t)blockIdx.z * K * N;
    const int tx = threadIdx.x & 31, ty = threadIdx.x >> 5;
    const float* src = in + bo;
    u16* dst = out + bo;
    #pragma unroll
    for (int r = ty; r < 32; r += 8) t[r][tx] = src[(size_t)(k0 + r) * N + n0 + tx];
    __syncthreads();
    #pragma unroll
    for (int r = ty; r < 32; r += 8) dst[(size_t)(n0 + r) * K + k0 + tx] = f2bf(t[tx][r]);
}

// merged kw/vw/ow transpose: z = sel*4 + layer, sel in {0,1,2}; 512x512 each
__global__ __launch_bounds__(256) void tconv3_kernel(
    const float* __restrict__ kw, const float* __restrict__ vw, const float* __restrict__ ow,
    u16* __restrict__ kwt, u16* __restrict__ vwt, u16* __restrict__ owt)
{
    __shared__ float t[32][33];
    const int z = blockIdx.z;
    const int sel = z >> 2, li = z & 3;
    const float* in = (sel == 0) ? kw : (sel == 1) ? vw : ow;
    u16* outp = (sel == 0) ? kwt : (sel == 1) ? vwt : owt;
    const size_t bo = (size_t)li * 262144;
    const int n0 = blockIdx.x * 32, k0 = blockIdx.y * 32;
    const int tx = threadIdx.x & 31, ty = threadIdx.x >> 5;
    const float* src = in + bo;
    u16* dst = outp + bo;
    #pragma unroll
    for (int r = ty; r < 32; r += 8) t[r][tx] = src[(size_t)(k0 + r) * 512 + n0 + tx];
    __syncthreads();
    #pragma unroll
    for (int r = ty; r < 32; r += 8) dst[(size_t)(n0 + r) * 512 + k0 + tx] = f2bf(t[tx][r]);
}

// transpose + hi/lo bf16 split: in [K][N] fp32 -> outh/outl [N][K] bf16
__global__ __launch_bounds__(256) void tconv_hilo_kernel(
    const float* __restrict__ in, u16* __restrict__ outh, u16* __restrict__ outl,
    int K, int N)
{
    __shared__ float t[32][33];
    const int n0 = blockIdx.x * 32, k0 = blockIdx.y * 32;
    const int tx = threadIdx.x & 31, ty = threadIdx.x >> 5;
    #pragma unroll
    for (int r = ty; r < 32; r += 8) t[r][tx] = in[(size_t)(k0 + r) * N + n0 + tx];
    __syncthreads();
    #pragma unroll
    for (int r = ty; r < 32; r += 8) {
        float v = t[tx][r];
        u16 h = f2bf(v);
        outh[(size_t)(n0 + r) * K + k0 + tx] = h;
        outl[(size_t)(n0 + r) * K + k0 + tx] = f2bf(v - bf2f(h));
    }
}

// ---------------------------------------------------------------------------
__global__ void pe_kernel(float* __restrict__ pe)
{
    int idx = blockIdx.x * 256 + threadIdx.x;
    int s = idx >> 9, d = idx & 511;
    float div = expf((float)(d & ~1) * (-9.210340371976184f / 512.0f));
    float ang = (float)s * div;
    pe[idx] = (d & 1) ? cosf(ang) : sinf(ang);
}

// ---------------------------------------------------------------------------
// moe_ln + y fused: one block per row r. Also writes yb row = bf16(qa + pe).
__global__ __launch_bounds__(64) void moe_ln_kernel(
    const u16* __restrict__ experts, const float* __restrict__ gates,
    const float* __restrict__ g, const float* __restrict__ bb,
    const float* __restrict__ pe, const float* __restrict__ qa,
    float* __restrict__ x, u16* __restrict__ xb, u16* __restrict__ yb)
{
    const int r = blockIdx.x, t = threadIdx.x;
    const u16* e = experts + (size_t)r * 2048;
    const float g0 = gates[r * 4 + 0], g1 = gates[r * 4 + 1];
    const float g2 = gates[r * 4 + 2], g3 = gates[r * 4 + 3];
    float v[8];
    #pragma unroll
    for (int it = 0; it < 8; ++it) {
        int d = t + it * 64;
        v[it] = g0 * bf2f(e[d]) + g1 * bf2f(e[512 + d])
              + g2 * bf2f(e[1024 + d]) + g3 * bf2f(e[1536 + d]);
    }
    float s = 0.f;
    #pragma unroll
    for (int it = 0; it < 8; ++it) s += v[it];
    s = wave_sum(s);
    const float mu = s * (1.f / 512.f);
    float q = 0.f;
    #pragma unroll
    for (int it = 0; it < 8; ++it) { float dd = v[it] - mu; q += dd * dd; }
    q = wave_sum(q);
    const float rstd = rsqrtf(q * (1.f / 512.f) + 1e-5f);
    const float* per = pe + (size_t)(r & 1023) * 512;
    #pragma unroll
    for (int it = 0; it < 8; ++it) {
        int d = t + it * 64;
        float pv = per[d];
        float o = (v[it] - mu) * rstd * g[d] + bb[d] + pv;
        x[(size_t)r * 512 + d] = o;
        xb[(size_t)r * 512 + d] = f2bf(o);
        yb[(size_t)r * 512 + d] = f2bf(qa[(size_t)r * 512 + d] + pv);
    }
}

// x = LN(x + t0 [+ t1] [+ bias])*g + b; writes x fp32, xb bf16, optional out2.
__global__ __launch_bounds__(64) void add_ln_kernel(
    float* __restrict__ x, u16* __restrict__ xb,
    const float* __restrict__ t0, const float* __restrict__ t1,
    const float* __restrict__ bias,
    const float* __restrict__ g, const float* __restrict__ bb,
    float* __restrict__ out2)
{
    const int r = blockIdx.x, t = threadIdx.x;
    float* xr = x + (size_t)r * 512;
    float v[8];
    #pragma unroll
    for (int it = 0; it < 8; ++it) {
        int d = t + it * 64;
        float tv = t0[(size_t)r * 512 + d];
        if (t1) tv += t1[(size_t)r * 512 + d];
        if (bias) tv += bias[d];
        v[it] = xr[d] + tv;
    }
    float s = 0.f;
    #pragma unroll
    for (int it = 0; it < 8; ++it) s += v[it];
    s = wave_sum(s);
    const float mu = s * (1.f / 512.f);
    float q = 0.f;
    #pragma unroll
    for (int it = 0; it < 8; ++it) { float dd = v[it] - mu; q += dd * dd; }
    q = wave_sum(q);
    const float rstd = rsqrtf(q * (1.f / 512.f) + 1e-5f);
    #pragma unroll
    for (int it = 0; it < 8; ++it) {
        int d = t + it * 64;
        float o = (v[it] - mu) * rstd * g[d] + bb[d];
        xr[d] = o;
        xb[(size_t)r * 512 + d] = f2bf(o);
        if (out2) out2[(size_t)r * 512 + d] = o;
    }
}

// ---------------------------------------------------------------------------
// MFMA flash strict-causal attention. Q=K=kh (bf16, [token][h*64+d]),
// V=vhT (bf16, pre-transposed: vhT[(b*512 + h*64 + d)*1024 + s]), ctx bf16.
// Single barrier per K/V tile: Q staging and Ps (softmax->PV) are WAVE-LOCAL
// (wave w only touches rows w*16..w*16+15); K/V double-buffered with T14
// reg-staging (global loads issued before compute, LDS writes after).
// ---------------------------------------------------------------------------
__global__ __launch_bounds__(256) void attn_kernel(
    const u16* __restrict__ kh, const u16* __restrict__ vhT,
    u16* __restrict__ ctx)
{
    __shared__ __align__(16) u16 Qs[64 * 64];      // [row][d]       wave-local
    __shared__ __align__(16) u16 Ks[2][64 * 64];   // [key][d]       dbuf
    __shared__ __align__(16) u16 Vt[2][64 * 72];   // [d][key]       dbuf
    __shared__ __align__(16) u16 Ps[64 * 72];      // [row][key]     wave-local

    const int tid = threadIdx.x;
    const int lane = tid & 63, wave = tid >> 6;
    const int quad = lane >> 4, fm = lane & 15;
    const int b = blockIdx.x, h = blockIdx.y;
    const int bz = blockIdx.z;
    const int it = (bz < 8) ? bz : (23 - bz);

    const u16* khb = kh + ((size_t)b * 1024) * 512 + h * 64;
    const u16* vtb = vhT + ((size_t)(b * 512 + h * 64)) * 1024;

    const int lj = tid >> 2;    // 0..63
    const int lc = tid & 3;

    {   // Q tile [row][d] -- wave-local (wave w writes rows w*16..w*16+15)
        const u16* src = khb + (size_t)(it * 64 + lj) * 512 + lc * 16;
        *(uint4*)&Qs[lj * 64 + lc * 16]     = *(const uint4*)src;
        *(uint4*)&Qs[lj * 64 + lc * 16 + 8] = *(const uint4*)(src + 8);
    }

    // prologue: stage K/V tile 0 into buffer 0
    {
        const u16* ksrc = khb + (size_t)(lj) * 512 + lc * 16;
        *(uint4*)&Ks[0][lj * 64 + lc * 16]     = *(const uint4*)ksrc;
        *(uint4*)&Ks[0][lj * 64 + lc * 16 + 8] = *(const uint4*)(ksrc + 8);
        const u16* vsrc = vtb + (size_t)lj * 1024 + lc * 16;
        *(uint4*)&Vt[0][lj * 72 + lc * 16]     = *(const uint4*)vsrc;
        *(uint4*)&Vt[0][lj * 72 + lc * 16 + 8] = *(const uint4*)(vsrc + 8);
    }

    const floatx4 zz = {0.f, 0.f, 0.f, 0.f};
    floatx4 o_acc[4];
    #pragma unroll
    for (int nt = 0; nt < 4; ++nt) o_acc[nt] = zz;
    float m_run[4] = { -INFINITY, -INFINITY, -INFINITY, -INFINITY };
    float l_run[4] = {};

    __syncthreads();

    for (int jt = 0; jt <= it; ++jt) {
        const int cur = jt & 1;
        const bool pf = (jt < it);

        // T14 issue-early: next tile's global loads into registers
        uint4 kr0, kr1, vr0, vr1;
        if (pf) {
            const u16* ksrc = khb + (size_t)((jt + 1) * 64 + lj) * 512 + lc * 16;
            kr0 = *(const uint4*)ksrc;
            kr1 = *(const uint4*)(ksrc + 8);
            const u16* vsrc = vtb + (size_t)lj * 1024 + (jt + 1) * 64 + lc * 16;
            vr0 = *(const uint4*)vsrc;
            vr1 = *(const uint4*)(vsrc + 8);
        }

        // ---- QK^T (Ks[cur] synced by previous barrier) ----
        floatx4 s_acc[4];
        #pragma unroll
        for (int nt = 0; nt < 4; ++nt) s_acc[nt] = zz;
        #pragma unroll
        for (int ks = 0; ks < 2; ++ks) {
            short8 af = *(const short8*)&Qs[(wave * 16 + fm) * 64 + ks * 32 + quad * 8];
            #pragma unroll
            for (int nt = 0; nt < 4; ++nt) {
                short8 bf = *(const short8*)&Ks[cur][(nt * 16 + fm) * 64 + ks * 32 + quad * 8];
                s_acc[nt] = __builtin_amdgcn_mfma_f32_16x16x32_bf16(af, bf, s_acc[nt], 0, 0, 0);
            }
        }

        // ---- scale + strict mask + online softmax (Ps wave-local) ----
        const bool diag = (jt == it);
        #pragma unroll
        for (int r = 0; r < 4; ++r) {
            const int rowi = wave * 16 + quad * 4 + r;
            float sv[4];
            #pragma unroll
            for (int nt = 0; nt < 4; ++nt) {
                float s = s_acc[nt][r] * 0.125f;
                if (diag && (nt * 16 + fm) >= rowi) s = -INFINITY;
                sv[nt] = s;
            }
            float mx = fmaxf(fmaxf(sv[0], sv[1]), fmaxf(sv[2], sv[3]));
            #pragma unroll
            for (int off = 1; off < 16; off <<= 1) mx = fmaxf(mx, __shfl_xor(mx, off));
            const float mn = fmaxf(m_run[r], mx);
            const float mfix = (mn == -INFINITY) ? 0.f : mn;
            const float alpha = (m_run[r] == -INFINITY) ? 0.f : __expf(m_run[r] - mn);
            m_run[r] = mn;
            float rs = 0.f;
            #pragma unroll
            for (int nt = 0; nt < 4; ++nt) {
                float p = __expf(sv[nt] - mfix);
                Ps[rowi * 72 + nt * 16 + fm] = f2bf(p);
                rs += p;
            }
            #pragma unroll
            for (int off = 1; off < 16; off <<= 1) rs += __shfl_xor(rs, off);
            l_run[r] = l_run[r] * alpha + rs;
            #pragma unroll
            for (int nt = 0; nt < 4; ++nt) o_acc[nt][r] *= alpha;
        }

        // ---- PV (Ps: same-wave rows; Vt[cur]: synced by previous barrier) ----
        #pragma unroll
        for (int ks = 0; ks < 2; ++ks) {
            short8 af = *(const short8*)&Ps[(wave * 16 + fm) * 72 + ks * 32 + quad * 8];
            #pragma unroll
            for (int nt = 0; nt < 4; ++nt) {
                short8 bf = *(const short8*)&Vt[cur][(nt * 16 + fm) * 72 + ks * 32 + quad * 8];
                o_acc[nt] = __builtin_amdgcn_mfma_f32_16x16x32_bf16(af, bf, o_acc[nt], 0, 0, 0);
            }
        }

        // T14 write-late: store prefetched tile, single barrier publishes it.
        if (pf) {
            *(uint4*)&Ks[cur ^ 1][lj * 64 + lc * 16]     = kr0;
            *(uint4*)&Ks[cur ^ 1][lj * 64 + lc * 16 + 8] = kr1;
            *(uint4*)&Vt[cur ^ 1][lj * 72 + lc * 16]     = vr0;
            *(uint4*)&Vt[cur ^ 1][lj * 72 + lc * 16 + 8] = vr1;
            __syncthreads();
        }
    }

    u16* cb = ctx + ((size_t)b * 1024 + (size_t)it * 64 + wave * 16) * 512 + h * 64;
    #pragma unroll
    for (int r = 0; r < 4; ++r) {
        const int row = quad * 4 + r;
        const float inv = (l_run[r] > 0.f) ? 1.f / l_run[r] : 0.f;
        #pragma unroll
        for (int nt = 0; nt < 4; ++nt)
            cb[(size_t)row * 512 + nt * 16 + fm] = f2bf(o_acc[nt][r] * inv);
    }
}

// ---------------------------------------------------------------------------
extern "C" void kernel_launch(void* const* d_in, const int* in_sizes, int n_in,
                              void* d_out, int out_size, void* d_ws, size_t ws_size,
                              hipStream_t stream)
{
    const float* q_raw   = (const float*)d_in[0];
    const float* m_seq   = (const float*)d_in[1];
    const float* qa      = (const float*)d_in[2];
    const float* exp_w1  = (const float*)d_in[3];
    const float* exp_b1  = (const float*)d_in[4];
    const float* exp_w2  = (const float*)d_in[5];
    const float* exp_b2  = (const float*)d_in[6];
    const float* adapt_w = (const float*)d_in[7];
    const float* adapt_b = (const float*)d_in[8];
    const float* gate_w  = (const float*)d_in[9];
    const float* gate_b  = (const float*)d_in[10];
    const float* moe_g   = (const float*)d_in[11];
    const float* moe_b   = (const float*)d_in[12];
    const float* kw      = (const float*)d_in[13];
    const float* kb      = (const float*)d_in[14];
    const float* vw      = (const float*)d_in[15];
    const float* vb      = (const float*)d_in[16];
    const float* ow      = (const float*)d_in[17];
    const float* ob      = (const float*)d_in[18];
    const float* ln1g    = (const float*)d_in[19];
    const float* ln1b    = (const float*)d_in[20];
    const float* fw1     = (const float*)d_in[21];
    const float* fb1     = (const float*)d_in[22];
    const float* fw2     = (const float*)d_in[23];
    const float* fb2     = (const float*)d_in[24];
    const float* ln2g    = (const float*)d_in[25];
    const float* ln2b    = (const float*)d_in[26];
    float* out = (float*)d_out;

    const size_t NEED = 125829120ull;
    if (ws_size < NEED) return;

    char* base = (char*)d_ws;
    float* x  = (float*)(base + 0);
    u16*  xb  = (u16*)(base + 8388608);
    u16*  yb  = (u16*)(base + 12582912);
    char* G = base + 16777216;
    // ---- MoE phase ----
    u16*   w1t     = (u16*)(G + 0);
    u16*   w2t     = (u16*)(G + 4718592);
    float* psum    = (float*)(G + 7864320);
    u16*   h1b4    = (u16*)(G + 7864320);      // over psum (disjoint lifetime)
    u16*   expb    = (u16*)(G + 33030144);
    float* pe      = (float*)(G + 49807360);
    float* gates   = (float*)(G + 51904512);
    u16*   adwh    = (u16*)(G + 52428800);     // adapt_w^T hi plane [512][3072]
    u16*   adwl    = (u16*)(G + 55574528);     // adapt_w^T lo plane [512][3072]
    u16*   qhi     = (u16*)(G + 58720256);     // q_raw hi bf16 plane [4096][3072]
    u16*   qlo     = (u16*)(G + 83886080);     // q_raw lo bf16 plane [4096][3072]
    // ---- layer phase (dead during MoE; qhi overlap w/ ffhb is lifetime-safe) ----
    u16*   kwt  = (u16*)(G + 0);
    u16*   vwt  = (u16*)(G + 2097152);
    u16*   owt  = (u16*)(G + 4194304);
    u16*   fw1t = (u16*)(G + 6291456);
    u16*   fw2t = (u16*)(G + 14680064);
    u16*   khb  = (u16*)(G + 23068672);
    u16*   vhT  = (u16*)(G + 27262976);
    u16*   ctxb = (u16*)(G + 31457280);
    float* p    = (float*)(G + 35651584);
    u16*   ffhb = (u16*)(G + 44040192);
    // FFN2 split-K partials (khb/vhT/ctxb/p all dead during FFN2)
    float* ps0  = (float*)(G + 23068672);      // 2 x 2097152 floats

    pe_kernel<<<2048, 256, 0, stream>>>(pe);
    hilo_conv_kernel<<<6144, 256, 0, stream>>>(q_raw, qhi, qlo);
    tconv_kernel<<<dim3(24, 24, 4), 256, 0, stream>>>(exp_w1, w1t, 768, 768);
    tconv_kernel<<<dim3(16, 24, 4), 256, 0, stream>>>(exp_w2, w2t, 768, 512);
    tconv_hilo_kernel<<<dim3(16, 96), 256, 0, stream>>>(adapt_w, adwh, adwl, 3072, 512);

    // ---- adapter + gate (split-bf16 MFMA, 3-term: ~2^-17 rel error) ----
    gemm_f32split<<<512, 256, 0, stream>>>(
        qhi, qlo, 3072, adwh, adwl, 3072, psum, 512, 2097152L, 768);
    gate_fused_kernel<<<4096, 64, 0, stream>>>(
        psum, adapt_b, m_seq, gate_w, gate_b, gates);

    // ---- experts (h1 A = qhi: bit-identical to in-kernel bf16 cast) ----
    gemm_bf16<u16><<<768, 256, 0, stream>>>(          // NT=6, 32m x 4z
        qhi, 3072, 768L, w1t, 768, 589824L, exp_b1, 768,
        nullptr, h1b4, 768, 3145728L, 768, 1, 0, 6);
    gemm_bf16<u16><<<512, 256, 0, stream>>>(          // NT=4, 32m x 4z
        h1b4, 768, 3145728L, w2t, 768, 393216L, exp_b2, 512,
        nullptr, expb, 2048, 512L, 768, 0, 0, 4);
    moe_ln_kernel<<<4096, 64, 0, stream>>>(expb, gates, moe_g, moe_b, pe, qa, x, xb, yb);

    // ---- layer weight conversions ----
    tconv3_kernel<<<dim3(16, 16, 12), 256, 0, stream>>>(kw, vw, ow, kwt, vwt, owt);
    tconv_kernel<<<dim3(64, 16, 4), 256, 0, stream>>>(fw1, fw1t, 512, 2048);
    tconv_kernel<<<dim3(16, 64, 4), 256, 0, stream>>>(fw2, fw2t, 2048, 512);

    // ---- transformer layers ----
    for (int i = 0; i < 4; ++i) {
        gemm_kv<<<256, 256, 0, stream>>>(
            xb, yb, kwt + (size_t)i * 262144, vwt + (size_t)i * 262144,
            kb + i * 512, vb + i * 512, khb, vhT);
        attn_kernel<<<dim3(4, 8, 16), 256, 0, stream>>>(khb, vhT, ctxb);
        gemm_bf16<u16><<<128, 256, 0, stream>>>(      // NT=4, 32m x 1z
            ctxb, 512, 0L, owt + (size_t)i * 262144, 512, 0L, ob + i * 512, 0,
            p, nullptr, 512, 0L, 512, 0, 0, 4);
        add_ln_kernel<<<4096, 64, 0, stream>>>(
            x, xb, p, nullptr, nullptr, ln1g + i * 512, ln1b + i * 512, nullptr);
        gemm_bf16<u16><<<512, 256, 0, stream>>>(      // NT=16, 32m x 1z
            xb, 512, 0L, fw1t + (size_t)i * 1048576, 512, 0L, fb1 + i * 2048, 0,
            nullptr, ffhb, 2048, 0L, 512, 1, 0, 16);
        gemm_bf16<u16><<<256, 256, 0, stream>>>(      // split-K=2: NT=4, 32m x 2z
            ffhb, 2048, 1024L, fw2t + (size_t)i * 1048576, 2048, 1024L, nullptr, 0,
            ps0, nullptr, 512, 2097152L, 1024, 0, 0, 4);
        add_ln_kernel<<<4096, 64, 0, stream>>>(
            x, xb, ps0, ps0 + 2097152, fb2 + i * 512,
            ln2g + i * 512, ln2b + i * 512, (i == 3) ? out : nullptr);
    }
}

// Round 10
// 798.630 us; speedup vs baseline: 1.2373x; 1.2373x over previous
//
#include <hip/hip_runtime.h>
#include <hip/hip_bf16.h>

typedef unsigned short u16;
typedef __attribute__((ext_vector_type(8))) short short8;
typedef __attribute__((ext_vector_type(4))) float floatx4;

__device__ __forceinline__ float bf2f(u16 u) {
    unsigned x = (unsigned)u << 16;
    return __uint_as_float(x);
}
__device__ __forceinline__ u16 f2bf(float f) {   // round-to-nearest-even
    unsigned x = __float_as_uint(f);
    unsigned r = (x + 0x7fffu + ((x >> 16) & 1u)) >> 16;
    return (u16)r;
}

__device__ __forceinline__ float wave_sum(float v) {
    #pragma unroll
    for (int off = 32; off; off >>= 1) v += __shfl_xor(v, off);
    return v;
}

// async global->LDS, 16B per lane; lds base must be wave-uniform (HW adds lane*16)
__device__ __forceinline__ void async16(const u16* g, const u16* lds) {
    __builtin_amdgcn_global_load_lds(
        (const __attribute__((address_space(1))) void*)g,
        (__attribute__((address_space(3))) void*)lds, 16, 0, 0);
}

// fp32 -> (hi, lo) bf16 split (8 elems). lo = bf16(v - fp32(hi)) exactly.
__device__ __forceinline__ void hilo8(const float* p, u16* hi, u16* lo) {
    float4 a = *(const float4*)p, b = *(const float4*)(p + 4);
    float v[8] = {a.x, a.y, a.z, a.w, b.x, b.y, b.z, b.w};
    #pragma unroll
    for (int i = 0; i < 8; ++i) {
        u16 h = f2bf(v[i]);
        hi[i] = h;
        lo[i] = f2bf(v[i] - bf2f(h));
    }
}

// whole-tensor fp32 -> hi/lo bf16 planes (8 elems/thread, coalesced)
__global__ __launch_bounds__(256) void hilo_conv_kernel(
    const float* __restrict__ in, u16* __restrict__ hi, u16* __restrict__ lo)
{
    const size_t i = ((size_t)blockIdx.x * 256 + threadIdx.x) * 8;
    u16 h[8], l[8];
    hilo8(in + i, h, l);
    *(uint4*)&hi[i] = *(const uint4*)h;
    *(uint4*)&lo[i] = *(const uint4*)l;
}

// ---------------------------------------------------------------------------
// bf16 MFMA GEMM body: C = act(A @ B + bias). Bt = B^T [N][K] bf16.
// BM x 128 tile / 256 threads / 4 waves, MT = m-frags per wave (4 -> BM=128,
// 2 -> BM=64). BK=64 per barrier pair, SINGLE-buffered LDS, plain
// __syncthreads (R7 dbuf and R9 counted-vmcnt both measured slower -- the
// compiler's drain is unavoidable; we hide it with co-resident blocks
// instead: BM=64 gives 24 KB LDS and 2x the grid, so 2-6 blocks/CU whose
// drains overlap via TLP).
// K must be a multiple of 64. transC: Cb written V-transposed.
// ---------------------------------------------------------------------------
template <int MT>
__device__ __forceinline__ void gemm_body(
    const u16* __restrict__ A, int lda,
    const u16* __restrict__ Bt, int ldb,
    const float* __restrict__ bias,
    float* __restrict__ Cf, u16* __restrict__ Cb, int ldc,
    int K, int act, int transC, int m0, int n0)
{
    constexpr int AHALF = MT * 32 * 32;          // u16 per BK=32 half of A
    __shared__ __align__(16) u16 Asm[2 * AHALF];
    __shared__ __align__(16) u16 Bsm[2 * 4096];

    const int tid = threadIdx.x;
    const int lane = tid & 63;
    const int wave = tid >> 6;
    const int wm = (wave >> 1) * (MT * 16), wn = (wave & 1) * 64;

    const int r0 = tid >> 2;
    const int kc = (tid & 3) * 8;
    const int kq = (lane >> 4) * 8;
    const int fm = lane & 15;

    const floatx4 zz = {0.f, 0.f, 0.f, 0.f};
    floatx4 acc[MT][4];
    #pragma unroll
    for (int mt = 0; mt < MT; ++mt)
        #pragma unroll
        for (int nt = 0; nt < 4; ++nt) acc[mt][nt] = zz;

    const u16* ldsA = Asm + wave * 512;          // + lane*16B implicit
    const u16* ldsB = Bsm + wave * 512;

    for (int kt = 0; kt < K; kt += 64) {
        #pragma unroll
        for (int h = 0; h < 2; ++h) {
            async16(&A[(size_t)(m0 + r0) * lda + kt + h * 32 + kc], ldsA + h * AHALF);
            if constexpr (MT == 4)
                async16(&A[(size_t)(m0 + r0 + 64) * lda + kt + h * 32 + kc],
                        ldsA + h * AHALF + 2048);
            async16(&Bt[(size_t)(n0 + r0) * ldb + kt + h * 32 + kc],      ldsB + h * 4096);
            async16(&Bt[(size_t)(n0 + r0 + 64) * ldb + kt + h * 32 + kc], ldsB + h * 4096 + 2048);
        }
        __syncthreads();

        #pragma unroll
        for (int h = 0; h < 2; ++h) {
            short8 af[MT], bfr[4];
            #pragma unroll
            for (int mt = 0; mt < MT; ++mt)
                af[mt] = *(const short8*)&Asm[h * AHALF + (wm + mt * 16 + fm) * 32 + kq];
            #pragma unroll
            for (int nt = 0; nt < 4; ++nt)
                bfr[nt] = *(const short8*)&Bsm[h * 4096 + (wn + nt * 16 + fm) * 32 + kq];

            #pragma unroll
            for (int mt = 0; mt < MT; ++mt)
                #pragma unroll
                for (int nt = 0; nt < 4; ++nt)
                    acc[mt][nt] = __builtin_amdgcn_mfma_f32_16x16x32_bf16(
                        af[mt], bfr[nt], acc[mt][nt], 0, 0, 0);
        }
        __syncthreads();
    }

    const int cr = (lane >> 4) * 4;
    #pragma unroll
    for (int mt = 0; mt < MT; ++mt) {
        #pragma unroll
        for (int nt = 0; nt < 4; ++nt) {
            const int col = n0 + wn + nt * 16 + fm;
            const float bz = bias ? bias[col] : 0.f;
            #pragma unroll
            for (int r = 0; r < 4; ++r) {
                const int row = m0 + wm + mt * 16 + cr + r;
                float v = acc[mt][nt][r] + bz;
                if (act) v = fmaxf(v, 0.f);
                if (Cf) Cf[(size_t)row * ldc + col] = v;
                if (Cb) {
                    if (transC)
                        Cb[(((size_t)(row >> 10) * 512 + col) << 10) + (row & 1023)] = f2bf(v);
                    else
                        Cb[(size_t)row * ldc + col] = f2bf(v);
                }
            }
        }
    }
}

// XCD-swizzled launcher. 1-D grid of NT * MP * NZ blocks where MP = 4096/BM
// m-panels (must make MP*NZ divisible by 8 -- all callers OK). The NT n-tiles
// sharing one A-panel land on one XCD (hw: xcd = wgid % 8).
template <int MT>
__global__ __launch_bounds__(256) void gemm_bf16(
    const u16* __restrict__ A, int lda, long strideAz,
    const u16* __restrict__ Bt, int ldb, long strideBz,
    const float* __restrict__ bias, int strideBiasZ,
    float* __restrict__ Cf, u16* __restrict__ Cb, int ldc, long strideCz,
    int K, int act, int transC, int NT)
{
    constexpr int MP = 4096 / (MT * 32);
    const int wg   = blockIdx.x;
    const int xcd  = wg & 7;
    const int slot = wg >> 3;
    const int nt   = slot % NT;
    const int pg   = slot / NT;
    const int panel = xcd + 8 * pg;      // 0 .. MP*NZ-1
    const int my = panel % MP, mz = panel / MP;

    A  += (size_t)mz * strideAz;
    Bt += (size_t)mz * strideBz;
    const float* bz = bias ? bias + (size_t)mz * strideBiasZ : nullptr;
    if (Cf) Cf += (size_t)mz * strideCz;
    if (Cb) Cb += (size_t)mz * strideCz;
    gemm_body<MT>(A, lda, Bt, ldb, bz, Cf, Cb, ldc, K, act, transC,
                  my * (MT * 32), nt * 128);
}

// Fused K+V projection, swizzled, BM=64. 512 blocks: panel mz=0 -> khb =
// xb @ kw, mz=1 -> vhT = trans(yb @ vw).
__global__ __launch_bounds__(256) void gemm_kv(
    const u16* __restrict__ xb, const u16* __restrict__ yb,
    const u16* __restrict__ kwt, const u16* __restrict__ vwt,
    const float* __restrict__ kb, const float* __restrict__ vb,
    u16* __restrict__ khb, u16* __restrict__ vhT)
{
    const int wg   = blockIdx.x;
    const int xcd  = wg & 7;
    const int slot = wg >> 3;
    const int nt   = slot & 3;           // NT = 4
    const int pg   = slot >> 2;
    const int panel = xcd + 8 * pg;      // 0..127
    const int my = panel & 63, mz = panel >> 6;

    if (mz == 0)
        gemm_body<2>(xb, 512, kwt, 512, kb, nullptr, khb, 512, 512, 0, 0, my * 64, nt * 128);
    else
        gemm_body<2>(yb, 512, vwt, 512, vb, nullptr, vhT, 512, 512, 0, 1, my * 64, nt * 128);
}

// ---------------------------------------------------------------------------
// Split-precision MFMA GEMM for the gate/adapter path (top-k is discontinuous,
// so plain bf16 is not enough). 3-term: C = Ah@Bh + Al@Bh + Ah@Bl.
// 128x128 tile, BK=64 (two BK=32 planes -> 96 MFMA per barrier pair),
// single-buffered 64 KB LDS. XCD-swizzled 1-D grid of 512. (R8 form.)
// ---------------------------------------------------------------------------
__global__ __launch_bounds__(256) void gemm_f32split(
    const u16* __restrict__ Ah, const u16* __restrict__ Al, int lda,
    const u16* __restrict__ Bh, const u16* __restrict__ Bl, int ldb,
    float* __restrict__ Cf, int ldc, long strideCz,
    int kz)
{
    __shared__ __align__(16) u16 Ahs[2 * 128 * 32];
    __shared__ __align__(16) u16 Als[2 * 128 * 32];
    __shared__ __align__(16) u16 Bhs[2 * 128 * 32];
    __shared__ __align__(16) u16 Bls[2 * 128 * 32];

    const int wg   = blockIdx.x;
    const int xcd  = wg & 7;
    const int slot = wg >> 3;            // 0..63
    const int nt4  = slot & 3;           // n-tile within A-group
    const int g    = xcd + 8 * (slot >> 2);   // A-group 0..127
    const int my   = g & 31, mz = g >> 5;

    const int tid = threadIdx.x;
    const int lane = tid & 63;
    const int wave = tid >> 6;
    const int m0 = my * 128, n0 = nt4 * 128;
    const int wm = (wave >> 1) * 64, wn = (wave & 1) * 64;
    const int k0 = mz * kz;
    Cf += (size_t)mz * strideCz;

    const int r0 = tid >> 2;
    const int kc = (tid & 3) * 8;
    const int kq = (lane >> 4) * 8;
    const int fm = lane & 15;

    const floatx4 zz = {0.f, 0.f, 0.f, 0.f};
    floatx4 acc[4][4];
    #pragma unroll
    for (int mt = 0; mt < 4; ++mt)
        #pragma unroll
        for (int nt = 0; nt < 4; ++nt) acc[mt][nt] = zz;

    const u16* ldsAh = Ahs + wave * 512;         // + lane*16B implicit
    const u16* ldsAl = Als + wave * 512;
    const u16* ldsBh = Bhs + wave * 512;
    const u16* ldsBl = Bls + wave * 512;

    for (int kt = 0; kt < kz; kt += 64) {
        #pragma unroll
        for (int h = 0; h < 2; ++h) {
            const size_t ka = (size_t)(m0 + r0) * lda + k0 + kt + h * 32 + kc;
            const size_t kb = (size_t)(n0 + r0) * ldb + k0 + kt + h * 32 + kc;
            async16(&Ah[ka],                     ldsAh + h * 4096);
            async16(&Ah[ka + (size_t)64 * lda],  ldsAh + h * 4096 + 2048);
            async16(&Al[ka],                     ldsAl + h * 4096);
            async16(&Al[ka + (size_t)64 * lda],  ldsAl + h * 4096 + 2048);
            async16(&Bh[kb],                     ldsBh + h * 4096);
            async16(&Bh[kb + (size_t)64 * ldb],  ldsBh + h * 4096 + 2048);
            async16(&Bl[kb],                     ldsBl + h * 4096);
            async16(&Bl[kb + (size_t)64 * ldb],  ldsBl + h * 4096 + 2048);
        }
        __syncthreads();

        #pragma unroll
        for (int h = 0; h < 2; ++h) {
            short8 ah[4], al[4], bh[4], bl[4];
            #pragma unroll
            for (int mt = 0; mt < 4; ++mt) {
                ah[mt] = *(const short8*)&Ahs[h * 4096 + (wm + mt * 16 + fm) * 32 + kq];
                al[mt] = *(const short8*)&Als[h * 4096 + (wm + mt * 16 + fm) * 32 + kq];
            }
            #pragma unroll
            for (int nt = 0; nt < 4; ++nt) {
                bh[nt] = *(const short8*)&Bhs[h * 4096 + (wn + nt * 16 + fm) * 32 + kq];
                bl[nt] = *(const short8*)&Bls[h * 4096 + (wn + nt * 16 + fm) * 32 + kq];
            }

            #pragma unroll
            for (int mt = 0; mt < 4; ++mt)
                #pragma unroll
                for (int nt = 0; nt < 4; ++nt) {
                    acc[mt][nt] = __builtin_amdgcn_mfma_f32_16x16x32_bf16(
                        ah[mt], bh[nt], acc[mt][nt], 0, 0, 0);
                    acc[mt][nt] = __builtin_amdgcn_mfma_f32_16x16x32_bf16(
                        al[mt], bh[nt], acc[mt][nt], 0, 0, 0);
                    acc[mt][nt] = __builtin_amdgcn_mfma_f32_16x16x32_bf16(
                        ah[mt], bl[nt], acc[mt][nt], 0, 0, 0);
                }
        }
        __syncthreads();
    }

    const int cr = (lane >> 4) * 4;
    #pragma unroll
    for (int mt = 0; mt < 4; ++mt) {
        #pragma unroll
        for (int nt = 0; nt < 4; ++nt) {
            const int col = n0 + wn + nt * 16 + fm;
            #pragma unroll
            for (int r = 0; r < 4; ++r) {
                const int row = m0 + wm + mt * 16 + cr + r;
                Cf[(size_t)row * ldc + col] = acc[mt][nt][r];
            }
        }
    }
}

// ---------------------------------------------------------------------------
// Fused: summary-row = relu(sum of 4 split-K partials + bias), then gate
// logits + top-2 softmax. One block per row.
// ---------------------------------------------------------------------------
__global__ __launch_bounds__(64) void gate_fused_kernel(
    const float* __restrict__ ps, const float* __restrict__ adapt_b,
    const float* __restrict__ m_seq,
    const float* __restrict__ gw, const float* __restrict__ gb,
    float* __restrict__ gates)
{
    const int r = blockIdx.x, t = threadIdx.x;
    float p0 = 0.f, p1 = 0.f, p2 = 0.f, p3 = 0.f;
    const float* pr = ps + (size_t)r * 512;
    for (int j = t; j < 512; j += 64) {
        float v = pr[j] + pr[j + 2097152] + pr[j + 4194304] + pr[j + 6291456] + adapt_b[j];
        float s = fmaxf(v, 0.f);
        const float* g = gw + (size_t)j * 4;
        p0 += s * g[0]; p1 += s * g[1]; p2 += s * g[2]; p3 += s * g[3];
    }
    {
        float m = m_seq[(size_t)r * 64 + t];
        const float* g = gw + (size_t)(512 + t) * 4;
        p0 += m * g[0]; p1 += m * g[1]; p2 += m * g[2]; p3 += m * g[3];
    }
    p0 = wave_sum(p0); p1 = wave_sum(p1); p2 = wave_sum(p2); p3 = wave_sum(p3);
    if (t == 0) {
        float lg[4] = { p0 + gb[0], p1 + gb[1], p2 + gb[2], p3 + gb[3] };
        float m1 = -INFINITY, m2 = -INFINITY;
        #pragma unroll
        for (int k = 0; k < 4; ++k) {
            float v = lg[k];
            if (v > m1) { m2 = m1; m1 = v; }
            else if (v > m2) { m2 = v; }
        }
        float wv[4], s = 0.f;
        #pragma unroll
        for (int k = 0; k < 4; ++k) {
            wv[k] = (lg[k] >= m2) ? __expf(lg[k] - m1) : 0.f;
            s += wv[k];
        }
        float inv = 1.f / s;
        #pragma unroll
        for (int k = 0; k < 4; ++k) gates[(size_t)r * 4 + k] = wv[k] * inv;
    }
}

// ---------------------------------------------------------------------------
__global__ __launch_bounds__(256) void tconv_kernel(
    const float* __restrict__ in, u16* __restrict__ out, int K, int N)
{
    __shared__ float t[32][33];
    const int n0 = blockIdx.x * 32, k0 = blockIdx.y * 32;
    const size_t bo = (size_t)blockIdx.z * K * N;
    const int tx = threadIdx.x & 31, ty = threadIdx.x >> 5;
    const float* src = in + bo;
    u16* dst = out + bo;
    #pragma unroll
    for (int r = ty; r < 32; r += 8) t[r][tx] = src[(size_t)(k0 + r) * N + n0 + tx];
    __syncthreads();
    #pragma unroll
    for (int r = ty; r < 32; r += 8) dst[(size_t)(n0 + r) * K + k0 + tx] = f2bf(t[tx][r]);
}

// merged kw/vw/ow transpose: z = sel*4 + layer, sel in {0,1,2}; 512x512 each
__global__ __launch_bounds__(256) void tconv3_kernel(
    const float* __restrict__ kw, const float* __restrict__ vw, const float* __restrict__ ow,
    u16* __restrict__ kwt, u16* __restrict__ vwt, u16* __restrict__ owt)
{
    __shared__ float t[32][33];
    const int z = blockIdx.z;
    const int sel = z >> 2, li = z & 3;
    const float* in = (sel == 0) ? kw : (sel == 1) ? vw : ow;
    u16* outp = (sel == 0) ? kwt : (sel == 1) ? vwt : owt;
    const size_t bo = (size_t)li * 262144;
    const int n0 = blockIdx.x * 32, k0 = blockIdx.y * 32;
    const int tx = threadIdx.x & 31, ty = threadIdx.x >> 5;
    const float* src = in + bo;
    u16* dst = outp + bo;
    #pragma unroll
    for (int r = ty; r < 32; r += 8) t[r][tx] = src[(size_t)(k0 + r) * 512 + n0 + tx];
    __syncthreads();
    #pragma unroll
    for (int r = ty; r < 32; r += 8) dst[(size_t)(n0 + r) * 512 + k0 + tx] = f2bf(t[tx][r]);
}

// transpose + hi/lo bf16 split: in [K][N] fp32 -> outh/outl [N][K] bf16
__global__ __launch_bounds__(256) void tconv_hilo_kernel(
    const float* __restrict__ in, u16* __restrict__ outh, u16* __restrict__ outl,
    int K, int N)
{
    __shared__ float t[32][33];
    const int n0 = blockIdx.x * 32, k0 = blockIdx.y * 32;
    const int tx = threadIdx.x & 31, ty = threadIdx.x >> 5;
    #pragma unroll
    for (int r = ty; r < 32; r += 8) t[r][tx] = in[(size_t)(k0 + r) * N + n0 + tx];
    __syncthreads();
    #pragma unroll
    for (int r = ty; r < 32; r += 8) {
        float v = t[tx][r];
        u16 h = f2bf(v);
        outh[(size_t)(n0 + r) * K + k0 + tx] = h;
        outl[(size_t)(n0 + r) * K + k0 + tx] = f2bf(v - bf2f(h));
    }
}

// ---------------------------------------------------------------------------
__global__ void pe_kernel(float* __restrict__ pe)
{
    int idx = blockIdx.x * 256 + threadIdx.x;
    int s = idx >> 9, d = idx & 511;
    float div = expf((float)(d & ~1) * (-9.210340371976184f / 512.0f));
    float ang = (float)s * div;
    pe[idx] = (d & 1) ? cosf(ang) : sinf(ang);
}

// ---------------------------------------------------------------------------
// moe_ln + y fused: one block per row r. Also writes yb row = bf16(qa + pe).
__global__ __launch_bounds__(64) void moe_ln_kernel(
    const u16* __restrict__ experts, const float* __restrict__ gates,
    const float* __restrict__ g, const float* __restrict__ bb,
    const float* __restrict__ pe, const float* __restrict__ qa,
    float* __restrict__ x, u16* __restrict__ xb, u16* __restrict__ yb)
{
    const int r = blockIdx.x, t = threadIdx.x;
    const u16* e = experts + (size_t)r * 2048;
    const float g0 = gates[r * 4 + 0], g1 = gates[r * 4 + 1];
    const float g2 = gates[r * 4 + 2], g3 = gates[r * 4 + 3];
    float v[8];
    #pragma unroll
    for (int it = 0; it < 8; ++it) {
        int d = t + it * 64;
        v[it] = g0 * bf2f(e[d]) + g1 * bf2f(e[512 + d])
              + g2 * bf2f(e[1024 + d]) + g3 * bf2f(e[1536 + d]);
    }
    float s = 0.f;
    #pragma unroll
    for (int it = 0; it < 8; ++it) s += v[it];
    s = wave_sum(s);
    const float mu = s * (1.f / 512.f);
    float q = 0.f;
    #pragma unroll
    for (int it = 0; it < 8; ++it) { float dd = v[it] - mu; q += dd * dd; }
    q = wave_sum(q);
    const float rstd = rsqrtf(q * (1.f / 512.f) + 1e-5f);
    const float* per = pe + (size_t)(r & 1023) * 512;
    #pragma unroll
    for (int it = 0; it < 8; ++it) {
        int d = t + it * 64;
        float pv = per[d];
        float o = (v[it] - mu) * rstd * g[d] + bb[d] + pv;
        x[(size_t)r * 512 + d] = o;
        xb[(size_t)r * 512 + d] = f2bf(o);
        yb[(size_t)r * 512 + d] = f2bf(qa[(size_t)r * 512 + d] + pv);
    }
}

// x = LN(x + t0 [+ t1] [+ bias])*g + b; writes x fp32, xb bf16, optional out2.
__global__ __launch_bounds__(64) void add_ln_kernel(
    float* __restrict__ x, u16* __restrict__ xb,
    const float* __restrict__ t0, const float* __restrict__ t1,
    const float* __restrict__ bias,
    const float* __restrict__ g, const float* __restrict__ bb,
    float* __restrict__ out2)
{
    const int r = blockIdx.x, t = threadIdx.x;
    float* xr = x + (size_t)r * 512;
    float v[8];
    #pragma unroll
    for (int it = 0; it < 8; ++it) {
        int d = t + it * 64;
        float tv = t0[(size_t)r * 512 + d];
        if (t1) tv += t1[(size_t)r * 512 + d];
        if (bias) tv += bias[d];
        v[it] = xr[d] + tv;
    }
    float s = 0.f;
    #pragma unroll
    for (int it = 0; it < 8; ++it) s += v[it];
    s = wave_sum(s);
    const float mu = s * (1.f / 512.f);
    float q = 0.f;
    #pragma unroll
    for (int it = 0; it < 8; ++it) { float dd = v[it] - mu; q += dd * dd; }
    q = wave_sum(q);
    const float rstd = rsqrtf(q * (1.f / 512.f) + 1e-5f);
    #pragma unroll
    for (int it = 0; it < 8; ++it) {
        int d = t + it * 64;
        float o = (v[it] - mu) * rstd * g[d] + bb[d];
        xr[d] = o;
        xb[(size_t)r * 512 + d] = f2bf(o);
        if (out2) out2[(size_t)r * 512 + d] = o;
    }
}

// ---------------------------------------------------------------------------
// MFMA flash strict-causal attention. Q=K=kh (bf16, [token][h*64+d]),
// V=vhT (bf16, pre-transposed: vhT[(b*512 + h*64 + d)*1024 + s]), ctx bf16.
// Single barrier per K/V tile: Q staging and Ps (softmax->PV) are WAVE-LOCAL
// (wave w only touches rows w*16..w*16+15); K/V double-buffered with T14
// reg-staging (global loads issued before compute, LDS writes after).
// ---------------------------------------------------------------------------
__global__ __launch_bounds__(256) void attn_kernel(
    const u16* __restrict__ kh, const u16* __restrict__ vhT,
    u16* __restrict__ ctx)
{
    __shared__ __align__(16) u16 Qs[64 * 64];      // [row][d]       wave-local
    __shared__ __align__(16) u16 Ks[2][64 * 64];   // [key][d]       dbuf
    __shared__ __align__(16) u16 Vt[2][64 * 72];   // [d][key]       dbuf
    __shared__ __align__(16) u16 Ps[64 * 72];      // [row][key]     wave-local

    const int tid = threadIdx.x;
    const int lane = tid & 63, wave = tid >> 6;
    const int quad = lane >> 4, fm = lane & 15;
    const int b = blockIdx.x, h = blockIdx.y;
    const int bz = blockIdx.z;
    const int it = (bz < 8) ? bz : (23 - bz);

    const u16* khb = kh + ((size_t)b * 1024) * 512 + h * 64;
    const u16* vtb = vhT + ((size_t)(b * 512 + h * 64)) * 1024;

    const int lj = tid >> 2;    // 0..63
    const int lc = tid & 3;

    {   // Q tile [row][d] -- wave-local (wave w writes rows w*16..w*16+15)
        const u16* src = khb + (size_t)(it * 64 + lj) * 512 + lc * 16;
        *(uint4*)&Qs[lj * 64 + lc * 16]     = *(const uint4*)src;
        *(uint4*)&Qs[lj * 64 + lc * 16 + 8] = *(const uint4*)(src + 8);
    }

    // prologue: stage K/V tile 0 into buffer 0
    {
        const u16* ksrc = khb + (size_t)(lj) * 512 + lc * 16;
        *(uint4*)&Ks[0][lj * 64 + lc * 16]     = *(const uint4*)ksrc;
        *(uint4*)&Ks[0][lj * 64 + lc * 16 + 8] = *(const uint4*)(ksrc + 8);
        const u16* vsrc = vtb + (size_t)lj * 1024 + lc * 16;
        *(uint4*)&Vt[0][lj * 72 + lc * 16]     = *(const uint4*)vsrc;
        *(uint4*)&Vt[0][lj * 72 + lc * 16 + 8] = *(const uint4*)(vsrc + 8);
    }

    const floatx4 zz = {0.f, 0.f, 0.f, 0.f};
    floatx4 o_acc[4];
    #pragma unroll
    for (int nt = 0; nt < 4; ++nt) o_acc[nt] = zz;
    float m_run[4] = { -INFINITY, -INFINITY, -INFINITY, -INFINITY };
    float l_run[4] = {};

    __syncthreads();

    for (int jt = 0; jt <= it; ++jt) {
        const int cur = jt & 1;
        const bool pf = (jt < it);

        // T14 issue-early: next tile's global loads into registers
        uint4 kr0, kr1, vr0, vr1;
        if (pf) {
            const u16* ksrc = khb + (size_t)((jt + 1) * 64 + lj) * 512 + lc * 16;
            kr0 = *(const uint4*)ksrc;
            kr1 = *(const uint4*)(ksrc + 8);
            const u16* vsrc = vtb + (size_t)lj * 1024 + (jt + 1) * 64 + lc * 16;
            vr0 = *(const uint4*)vsrc;
            vr1 = *(const uint4*)(vsrc + 8);
        }

        // ---- QK^T (Ks[cur] synced by previous barrier) ----
        floatx4 s_acc[4];
        #pragma unroll
        for (int nt = 0; nt < 4; ++nt) s_acc[nt] = zz;
        #pragma unroll
        for (int ks = 0; ks < 2; ++ks) {
            short8 af = *(const short8*)&Qs[(wave * 16 + fm) * 64 + ks * 32 + quad * 8];
            #pragma unroll
            for (int nt = 0; nt < 4; ++nt) {
                short8 bf = *(const short8*)&Ks[cur][(nt * 16 + fm) * 64 + ks * 32 + quad * 8];
                s_acc[nt] = __builtin_amdgcn_mfma_f32_16x16x32_bf16(af, bf, s_acc[nt], 0, 0, 0);
            }
        }

        // ---- scale + strict mask + online softmax (Ps wave-local) ----
        const bool diag = (jt == it);
        #pragma unroll
        for (int r = 0; r < 4; ++r) {
            const int rowi = wave * 16 + quad * 4 + r;
            float sv[4];
            #pragma unroll
            for (int nt = 0; nt < 4; ++nt) {
                float s = s_acc[nt][r] * 0.125f;
                if (diag && (nt * 16 + fm) >= rowi) s = -INFINITY;
                sv[nt] = s;
            }
            float mx = fmaxf(fmaxf(sv[0], sv[1]), fmaxf(sv[2], sv[3]));
            #pragma unroll
            for (int off = 1; off < 16; off <<= 1) mx = fmaxf(mx, __shfl_xor(mx, off));
            const float mn = fmaxf(m_run[r], mx);
            const float mfix = (mn == -INFINITY) ? 0.f : mn;
            const float alpha = (m_run[r] == -INFINITY) ? 0.f : __expf(m_run[r] - mn);
            m_run[r] = mn;
            float rs = 0.f;
            #pragma unroll
            for (int nt = 0; nt < 4; ++nt) {
                float p = __expf(sv[nt] - mfix);
                Ps[rowi * 72 + nt * 16 + fm] = f2bf(p);
                rs += p;
            }
            #pragma unroll
            for (int off = 1; off < 16; off <<= 1) rs += __shfl_xor(rs, off);
            l_run[r] = l_run[r] * alpha + rs;
            #pragma unroll
            for (int nt = 0; nt < 4; ++nt) o_acc[nt][r] *= alpha;
        }

        // ---- PV (Ps: same-wave rows; Vt[cur]: synced by previous barrier) ----
        #pragma unroll
        for (int ks = 0; ks < 2; ++ks) {
            short8 af = *(const short8*)&Ps[(wave * 16 + fm) * 72 + ks * 32 + quad * 8];
            #pragma unroll
            for (int nt = 0; nt < 4; ++nt) {
                short8 bf = *(const short8*)&Vt[cur][(nt * 16 + fm) * 72 + ks * 32 + quad * 8];
                o_acc[nt] = __builtin_amdgcn_mfma_f32_16x16x32_bf16(af, bf, o_acc[nt], 0, 0, 0);
            }
        }

        // T14 write-late: store prefetched tile, single barrier publishes it.
        if (pf) {
            *(uint4*)&Ks[cur ^ 1][lj * 64 + lc * 16]     = kr0;
            *(uint4*)&Ks[cur ^ 1][lj * 64 + lc * 16 + 8] = kr1;
            *(uint4*)&Vt[cur ^ 1][lj * 72 + lc * 16]     = vr0;
            *(uint4*)&Vt[cur ^ 1][lj * 72 + lc * 16 + 8] = vr1;
            __syncthreads();
        }
    }

    u16* cb = ctx + ((size_t)b * 1024 + (size_t)it * 64 + wave * 16) * 512 + h * 64;
    #pragma unroll
    for (int r = 0; r < 4; ++r) {
        const int row = quad * 4 + r;
        const float inv = (l_run[r] > 0.f) ? 1.f / l_run[r] : 0.f;
        #pragma unroll
        for (int nt = 0; nt < 4; ++nt)
            cb[(size_t)row * 512 + nt * 16 + fm] = f2bf(o_acc[nt][r] * inv);
    }
}

// ---------------------------------------------------------------------------
extern "C" void kernel_launch(void* const* d_in, const int* in_sizes, int n_in,
                              void* d_out, int out_size, void* d_ws, size_t ws_size,
                              hipStream_t stream)
{
    const float* q_raw   = (const float*)d_in[0];
    const float* m_seq   = (const float*)d_in[1];
    const float* qa      = (const float*)d_in[2];
    const float* exp_w1  = (const float*)d_in[3];
    const float* exp_b1  = (const float*)d_in[4];
    const float* exp_w2  = (const float*)d_in[5];
    const float* exp_b2  = (const float*)d_in[6];
    const float* adapt_w = (const float*)d_in[7];
    const float* adapt_b = (const float*)d_in[8];
    const float* gate_w  = (const float*)d_in[9];
    const float* gate_b  = (const float*)d_in[10];
    const float* moe_g   = (const float*)d_in[11];
    const float* moe_b   = (const float*)d_in[12];
    const float* kw      = (const float*)d_in[13];
    const float* kb      = (const float*)d_in[14];
    const float* vw      = (const float*)d_in[15];
    const float* vb      = (const float*)d_in[16];
    const float* ow      = (const float*)d_in[17];
    const float* ob      = (const float*)d_in[18];
    const float* ln1g    = (const float*)d_in[19];
    const float* ln1b    = (const float*)d_in[20];
    const float* fw1     = (const float*)d_in[21];
    const float* fb1     = (const float*)d_in[22];
    const float* fw2     = (const float*)d_in[23];
    const float* fb2     = (const float*)d_in[24];
    const float* ln2g    = (const float*)d_in[25];
    const float* ln2b    = (const float*)d_in[26];
    float* out = (float*)d_out;

    const size_t NEED = 125829120ull;
    if (ws_size < NEED) return;

    char* base = (char*)d_ws;
    float* x  = (float*)(base + 0);
    u16*  xb  = (u16*)(base + 8388608);
    u16*  yb  = (u16*)(base + 12582912);
    char* G = base + 16777216;
    // ---- MoE phase ----
    u16*   w1t     = (u16*)(G + 0);
    u16*   w2t     = (u16*)(G + 4718592);
    float* psum    = (float*)(G + 7864320);
    u16*   h1b4    = (u16*)(G + 7864320);      // over psum (disjoint lifetime)
    u16*   expb    = (u16*)(G + 33030144);
    float* pe      = (float*)(G + 49807360);
    float* gates   = (float*)(G + 51904512);
    u16*   adwh    = (u16*)(G + 52428800);     // adapt_w^T hi plane [512][3072]
    u16*   adwl    = (u16*)(G + 55574528);     // adapt_w^T lo plane [512][3072]
    u16*   qhi     = (u16*)(G + 58720256);     // q_raw hi bf16 plane [4096][3072]
    u16*   qlo     = (u16*)(G + 83886080);     // q_raw lo bf16 plane [4096][3072]
    // ---- layer phase (dead during MoE; qhi overlap w/ ffhb is lifetime-safe) ----
    u16*   kwt  = (u16*)(G + 0);
    u16*   vwt  = (u16*)(G + 2097152);
    u16*   owt  = (u16*)(G + 4194304);
    u16*   fw1t = (u16*)(G + 6291456);
    u16*   fw2t = (u16*)(G + 14680064);
    u16*   khb  = (u16*)(G + 23068672);
    u16*   vhT  = (u16*)(G + 27262976);
    u16*   ctxb = (u16*)(G + 31457280);
    float* p    = (float*)(G + 35651584);
    u16*   ffhb = (u16*)(G + 44040192);
    // FFN2 split-K partials (khb/vhT/ctxb/p all dead during FFN2)
    float* ps0  = (float*)(G + 23068672);      // 2 x 2097152 floats

    pe_kernel<<<2048, 256, 0, stream>>>(pe);
    hilo_conv_kernel<<<6144, 256, 0, stream>>>(q_raw, qhi, qlo);
    tconv_kernel<<<dim3(24, 24, 4), 256, 0, stream>>>(exp_w1, w1t, 768, 768);
    tconv_kernel<<<dim3(16, 24, 4), 256, 0, stream>>>(exp_w2, w2t, 768, 512);
    tconv_hilo_kernel<<<dim3(16, 96), 256, 0, stream>>>(adapt_w, adwh, adwl, 3072, 512);

    // ---- adapter + gate (split-bf16 MFMA, 3-term: ~2^-17 rel error) ----
    gemm_f32split<<<512, 256, 0, stream>>>(
        qhi, qlo, 3072, adwh, adwl, 3072, psum, 512, 2097152L, 768);
    gate_fused_kernel<<<4096, 64, 0, stream>>>(
        psum, adapt_b, m_seq, gate_w, gate_b, gates);

    // ---- experts (h1 A = qhi: bit-identical to in-kernel bf16 cast) ----
    gemm_bf16<2><<<1536, 256, 0, stream>>>(           // BM=64: NT=6, 64m x 4z
        qhi, 3072, 768L, w1t, 768, 589824L, exp_b1, 768,
        nullptr, h1b4, 768, 3145728L, 768, 1, 0, 6);
    gemm_bf16<2><<<1024, 256, 0, stream>>>(           // BM=64: NT=4, 64m x 4z
        h1b4, 768, 3145728L, w2t, 768, 393216L, exp_b2, 512,
        nullptr, expb, 2048, 512L, 768, 0, 0, 4);
    moe_ln_kernel<<<4096, 64, 0, stream>>>(expb, gates, moe_g, moe_b, pe, qa, x, xb, yb);

    // ---- layer weight conversions ----
    tconv3_kernel<<<dim3(16, 16, 12), 256, 0, stream>>>(kw, vw, ow, kwt, vwt, owt);
    tconv_kernel<<<dim3(64, 16, 4), 256, 0, stream>>>(fw1, fw1t, 512, 2048);
    tconv_kernel<<<dim3(16, 64, 4), 256, 0, stream>>>(fw2, fw2t, 2048, 512);

    // ---- transformer layers ----
    for (int i = 0; i < 4; ++i) {
        gemm_kv<<<512, 256, 0, stream>>>(             // BM=64: NT=4, 64m x 2z
            xb, yb, kwt + (size_t)i * 262144, vwt + (size_t)i * 262144,
            kb + i * 512, vb + i * 512, khb, vhT);
        attn_kernel<<<dim3(4, 8, 16), 256, 0, stream>>>(khb, vhT, ctxb);
        gemm_bf16<2><<<256, 256, 0, stream>>>(        // BM=64: NT=4, 64m x 1z
            ctxb, 512, 0L, owt + (size_t)i * 262144, 512, 0L, ob + i * 512, 0,
            p, nullptr, 512, 0L, 512, 0, 0, 4);
        add_ln_kernel<<<4096, 64, 0, stream>>>(
            x, xb, p, nullptr, nullptr, ln1g + i * 512, ln1b + i * 512, nullptr);
        gemm_bf16<2><<<1024, 256, 0, stream>>>(       // BM=64: NT=16, 64m x 1z
            xb, 512, 0L, fw1t + (size_t)i * 1048576, 512, 0L, fb1 + i * 2048, 0,
            nullptr, ffhb, 2048, 0L, 512, 1, 0, 16);
        gemm_bf16<2><<<512, 256, 0, stream>>>(        // split-K=2, BM=64: NT=4, 64m x 2z
            ffhb, 2048, 1024L, fw2t + (size_t)i * 1048576, 2048, 1024L, nullptr, 0,
            ps0, nullptr, 512, 2097152L, 1024, 0, 0, 4);
        add_ln_kernel<<<4096, 64, 0, stream>>>(
            x, xb, ps0, ps0 + 2097152, fb2 + i * 512,
            ln2g + i * 512, ln2b + i * 512, (i == 3) ? out : nullptr);
    }
}